// Round 1
// baseline (47.312 us; speedup 1.0000x reference)
//
#include <hip/hip_runtime.h>

namespace {
constexpr int kFrame = 80;     // FRAME_SIZE
constexpr int kRad   = 2;      // RADIUS
constexpr int kW     = 5;      // 2*RADIUS+1
constexpr int kB     = 64;
constexpr int kF     = 4000;
constexpr int kN     = kFrame * kF;   // 320000 samples per batch row
}

template <bool CHECKED>
__device__ __forceinline__ float load_x(const float* __restrict__ xb, int s) {
    if constexpr (CHECKED) {
        // JAX pads 300 zeros in front (s<0 -> 0) and clamps OOB-high to last elem.
        int sc = s < 0 ? 0 : s;
        sc = sc > (kN - 1) ? (kN - 1) : sc;
        float v = xb[sc];
        return (s < 0) ? 0.0f : v;
    } else {
        return xb[s];
    }
}

template <bool CHECKED>
__device__ __forceinline__ void frame_acorr(const float* __restrict__ xb,
                                            int base, int lbase, float* res) {
    // Sliding 5-wide lag window: at iter t, w_k = x[lbase + t + k], k=0..4.
    float w0 = load_x<CHECKED>(xb, lbase + 0);
    float w1 = load_x<CHECKED>(xb, lbase + 1);
    float w2 = load_x<CHECKED>(xb, lbase + 2);
    float w3 = load_x<CHECKED>(xb, lbase + 3);
    float d0 = 0.f, d1 = 0.f, d2 = 0.f, d3 = 0.f, d4 = 0.f;
    float l0 = 0.f, l1 = 0.f, l2 = 0.f, l3 = 0.f, l4 = 0.f;
    float fn = 0.f;

#define ACORR_STEP(FT, T)                                                     \
    {                                                                         \
        float w4 = load_x<CHECKED>(xb, lbase + (T) + 4);                      \
        float ft = (FT);                                                      \
        fn += ft * ft;                                                        \
        d0 += ft * w0; d1 += ft * w1; d2 += ft * w2; d3 += ft * w3;           \
        d4 += ft * w4;                                                        \
        l0 += w0 * w0; l1 += w1 * w1; l2 += w2 * w2; l3 += w3 * w3;           \
        l4 += w4 * w4;                                                        \
        w0 = w1; w1 = w2; w2 = w3; w3 = w4;                                   \
    }

#pragma unroll
    for (int t4 = 0; t4 < kFrame; t4 += 4) {
        const float4 fr = *reinterpret_cast<const float4*>(xb + base + t4);
        ACORR_STEP(fr.x, t4 + 0);
        ACORR_STEP(fr.y, t4 + 1);
        ACORR_STEP(fr.z, t4 + 2);
        ACORR_STEP(fr.w, t4 + 3);
    }
#undef ACORR_STEP

    res[0] = d0 * rsqrtf(fn * l0 + 1e-9f);
    res[1] = d1 * rsqrtf(fn * l1 + 1e-9f);
    res[2] = d2 * rsqrtf(fn * l2 + 1e-9f);
    res[3] = d3 * rsqrtf(fn * l3 + 1e-9f);
    res[4] = d4 * rsqrtf(fn * l4 + 1e-9f);
}

__global__ __launch_bounds__(256)
void pitch_acorr_kernel(const float* __restrict__ x,
                        const int* __restrict__ periods,
                        float* __restrict__ out) {
    int tid = blockIdx.x * blockDim.x + threadIdx.x;
    if (tid >= kB * kF) return;
    int b = tid / kF;
    int f = tid - b * kF;
    const float* xb = x + (long long)b * kN;
    int p = periods[tid];            // periods laid out (B,F) -> index b*F+f == tid
    int base  = f * kFrame;
    int lbase = base - p - kRad;     // first lag sample index (may be negative)

    float res[kW];
    // Max lag index touched = lbase + 79 + 4; safe iff within [0, N-1].
    bool safe = (lbase >= 0) && (lbase + kFrame + 3 < kN);
    if (safe) frame_acorr<false>(xb, base, lbase, res);
    else      frame_acorr<true >(xb, base, lbase, res);

    float* o = out + (long long)tid * kW;
    o[0] = res[0]; o[1] = res[1]; o[2] = res[2]; o[3] = res[3]; o[4] = res[4];
}

extern "C" void kernel_launch(void* const* d_in, const int* in_sizes, int n_in,
                              void* d_out, int out_size, void* d_ws, size_t ws_size,
                              hipStream_t stream) {
    const float* x       = (const float*)d_in[0];
    const int*   periods = (const int*)d_in[1];
    float*       out     = (float*)d_out;

    const int total  = kB * kF;            // 256000 threads, one per frame
    const int block  = 256;
    const int grid   = (total + block - 1) / block;  // 1000
    pitch_acorr_kernel<<<grid, block, 0, stream>>>(x, periods, out);
}